// Round 1
// baseline (743.253 us; speedup 1.0000x reference)
//
#include <hip/hip_runtime.h>

#define NF   128
#define C1   16
#define C2   32
#define NCLS 10

// ---------- degree / norm ----------
__global__ void k_init_deg(float* __restrict__ deg, int N) {
    int i = blockIdx.x * blockDim.x + threadIdx.x;
    if (i < N) deg[i] = 1.0f;  // self-loop
}

__global__ void k_deg(const int* __restrict__ ei, float* __restrict__ deg, int E) {
    int e = blockIdx.x * blockDim.x + threadIdx.x;
    if (e < E) atomicAdd(&deg[ei[E + e]], 1.0f);  // dst in-degree
}

__global__ void k_dinv(const float* __restrict__ deg, float* __restrict__ dinv, int N) {
    int i = blockIdx.x * blockDim.x + threadIdx.x;
    if (i < N) dinv[i] = rsqrtf(deg[i]);
}

// ---------- linear 1: [N,128] @ [128,16] ----------
__global__ __launch_bounds__(256) void k_lin1(const float* __restrict__ x,
                                              const float* __restrict__ W1,
                                              float* __restrict__ h1, int N) {
    __shared__ float ws[NF * C1];     // 8 KB
    __shared__ float xs[16 * 132];    // 16 rows, padded stride 132 (bank-conflict-free)
    int tid = threadIdx.x;
    for (int t = tid; t < NF * C1; t += 256) ws[t] = W1[t];
    int n0 = blockIdx.x * 16;
    for (int t = tid; t < 16 * NF; t += 256) {
        int r = t >> 7, c = t & 127;
        int n = n0 + r;
        xs[r * 132 + c] = (n < N) ? x[n * NF + c] : 0.0f;
    }
    __syncthreads();
    int r = tid >> 4, j = tid & 15;   // 16 nodes x 16 outs
    float acc = 0.0f;
#pragma unroll 4
    for (int k = 0; k < NF; ++k) acc += xs[r * 132 + k] * ws[k * C1 + j];
    int n = n0 + r;
    if (n < N) h1[n * C1 + j] = acc;
}

// ---------- agg init: agg = h * dinv^2 (self-loop term) ----------
template <int LOG2C>
__global__ void k_agg_init(const float* __restrict__ h, const float* __restrict__ dinv,
                           float* __restrict__ agg, int total) {
    int i = blockIdx.x * blockDim.x + threadIdx.x;
    if (i < total) {
        float d = dinv[i >> LOG2C];
        agg[i] = h[i] * d * d;
    }
}

// ---------- edge scatter-add: agg[dst] += h[src] * dinv[src]*dinv[dst] ----------
template <int LOG2C>
__global__ __launch_bounds__(256) void k_edge(const int* __restrict__ ei,
                                              const float* __restrict__ dinv,
                                              const float* __restrict__ h,
                                              float* __restrict__ agg, int E) {
    int t = blockIdx.x * blockDim.x + threadIdx.x;
    int e = t >> LOG2C;
    int j = t & ((1 << LOG2C) - 1);
    if (e < E) {
        int s = ei[e], d = ei[E + e];
        float w = dinv[s] * dinv[d];
        atomicAdd(&agg[(d << LOG2C) + j], h[(s << LOG2C) + j] * w);
    }
}

// ---------- linear 2: relu(agg1+b1) @ [16,32] ----------
__global__ __launch_bounds__(256) void k_lin2(const float* __restrict__ agg1,
                                              const float* __restrict__ b1,
                                              const float* __restrict__ W2,
                                              float* __restrict__ h2, int N) {
    __shared__ float ws[C1 * C2];   // 512
    __shared__ float hs[8 * C1];    // 8 nodes x 16
    int tid = threadIdx.x;
    for (int t = tid; t < C1 * C2; t += 256) ws[t] = W2[t];
    int n0 = blockIdx.x * 8;
    if (tid < 8 * C1) {
        int r = tid >> 4, j = tid & 15;
        int n = n0 + r;
        hs[tid] = (n < N) ? fmaxf(agg1[n * C1 + j] + b1[j], 0.0f) : 0.0f;
    }
    __syncthreads();
    int r = tid >> 5, i = tid & 31;  // 8 nodes x 32 outs
    float acc = 0.0f;
#pragma unroll
    for (int j = 0; j < C1; ++j) acc += hs[r * C1 + j] * ws[j * C2 + i];
    int n = n0 + r;
    if (n < N) h2[n * C2 + i] = acc;
}

// ---------- per-graph mean pool (sorted batch) + fused FC ----------
__global__ __launch_bounds__(256) void k_pool_fc(const float* __restrict__ agg2,
                                                 const float* __restrict__ b2,
                                                 const int* __restrict__ batch,
                                                 const float* __restrict__ Wfc,
                                                 const float* __restrict__ bfc,
                                                 float* __restrict__ out, int N, int G) {
    int g = blockIdx.x;
    // lower_bound(batch, g) / lower_bound(batch, g+1)
    int lo = 0, hi = N;
    while (lo < hi) { int m = (lo + hi) >> 1; if (batch[m] < g) lo = m + 1; else hi = m; }
    int start = lo;
    lo = start; hi = N;
    while (lo < hi) { int m = (lo + hi) >> 1; if (batch[m] < g + 1) lo = m + 1; else hi = m; }
    int end = lo;

    int tid = threadIdx.x;
    int i = tid & 31, r = tid >> 5;   // 8 node-groups x 32 feats
    float bi = b2[i];
    float acc = 0.0f;
    for (int n = start + r; n < end; n += 8)
        acc += fmaxf(agg2[n * C2 + i] + bi, 0.0f);

    __shared__ float red[256];
    red[tid] = acc;
    __syncthreads();
    for (int s = 4; s >= 1; s >>= 1) {
        if (r < s) red[tid] += red[tid + s * 32];
        __syncthreads();
    }
    __shared__ float pooled[C2];
    if (tid < C2) {
        float cnt = (float)(end - start);
        pooled[tid] = red[tid] / fmaxf(cnt, 1.0f);
    }
    __syncthreads();
    if (tid < NCLS) {
        float a = bfc[tid];
#pragma unroll
        for (int j = 0; j < C2; ++j) a += pooled[j] * Wfc[j * NCLS + tid];
        out[g * NCLS + tid] = a;
    }
}

extern "C" void kernel_launch(void* const* d_in, const int* in_sizes, int n_in,
                              void* d_out, int out_size, void* d_ws, size_t ws_size,
                              hipStream_t stream) {
    const float* x    = (const float*)d_in[0];
    const int*   ei   = (const int*)d_in[1];
    const int*   batch= (const int*)d_in[2];
    const float* W1   = (const float*)d_in[3];
    const float* b1   = (const float*)d_in[4];
    const float* W2   = (const float*)d_in[5];
    const float* b2   = (const float*)d_in[6];
    const float* Wfc  = (const float*)d_in[7];
    const float* bfc  = (const float*)d_in[8];
    float* out = (float*)d_out;

    const int N = in_sizes[0] / NF;       // 100000
    const int E = in_sizes[1] / 2;        // 3200000
    const int G = out_size / NCLS;        // 256

    float* ws0 = (float*)d_ws;
    float* deg  = ws0;                    // N
    float* dinv = deg + N;                // N
    float* h1   = dinv + N;               // N*16
    float* agg1 = h1 + (size_t)N * C1;    // N*16
    float* h2   = agg1 + (size_t)N * C1;  // N*32
    float* agg2 = h2 + (size_t)N * C2;    // N*32

    const int B = 256;

    k_init_deg<<<(N + B - 1) / B, B, 0, stream>>>(deg, N);
    k_deg<<<(E + B - 1) / B, B, 0, stream>>>(ei, deg, E);
    k_dinv<<<(N + B - 1) / B, B, 0, stream>>>(deg, dinv, N);

    k_lin1<<<(N + 15) / 16, B, 0, stream>>>(x, W1, h1, N);
    k_agg_init<4><<<(N * C1 + B - 1) / B, B, 0, stream>>>(h1, dinv, agg1, N * C1);
    k_edge<4><<<((long long)E * C1 + B - 1) / B, B, 0, stream>>>(ei, dinv, h1, agg1, E);

    k_lin2<<<(N + 7) / 8, B, 0, stream>>>(agg1, b1, W2, h2, N);
    k_agg_init<5><<<(N * C2 + B - 1) / B, B, 0, stream>>>(h2, dinv, agg2, N * C2);
    k_edge<5><<<((long long)E * C2 + B - 1) / B, B, 0, stream>>>(ei, dinv, h2, agg2, E);

    k_pool_fc<<<G, B, 0, stream>>>(agg2, b2, batch, Wfc, bfc, out, N, G);
}

// Round 2
// 578.334 us; speedup vs baseline: 1.2852x; 1.2852x over previous
//
#include <hip/hip_runtime.h>

#define NF   128
#define C1   16
#define C2   32
#define NCLS 10

// ============ CSR build ============

__global__ void k_hist(const int* __restrict__ ei, int* __restrict__ cnt, int E) {
    int e = blockIdx.x * blockDim.x + threadIdx.x;
    if (e < E) atomicAdd(&cnt[ei[E + e]], 1);   // in-degree by dst
}

__global__ void k_dinv(const int* __restrict__ cnt, float* __restrict__ dinv, int N) {
    int i = blockIdx.x * blockDim.x + threadIdx.x;
    if (i < N) dinv[i] = rsqrtf((float)cnt[i] + 1.0f);  // +1 self-loop
}

// exclusive scan, 3-kernel (N=100k -> 391 block sums, scanned by one block)
__global__ __launch_bounds__(256) void k_scan1(const int* __restrict__ cnt,
                                               int* __restrict__ rowptr,
                                               int* __restrict__ bsum, int N) {
    __shared__ int sh[256];
    int i = blockIdx.x * 256 + threadIdx.x;
    int v = (i < N) ? cnt[i] : 0;
    sh[threadIdx.x] = v;
    __syncthreads();
    for (int off = 1; off < 256; off <<= 1) {
        int t = (threadIdx.x >= off) ? sh[threadIdx.x - off] : 0;
        __syncthreads();
        sh[threadIdx.x] += t;
        __syncthreads();
    }
    if (i < N) rowptr[i] = sh[threadIdx.x] - v;   // exclusive
    if (threadIdx.x == 255) bsum[blockIdx.x] = sh[255];
}

__global__ __launch_bounds__(512) void k_scan2(int* __restrict__ bsum, int nb) {
    __shared__ int sh[512];
    int tid = threadIdx.x;
    int v = (tid < nb) ? bsum[tid] : 0;
    sh[tid] = v;
    __syncthreads();
    for (int off = 1; off < 512; off <<= 1) {
        int t = (tid >= off) ? sh[tid - off] : 0;
        __syncthreads();
        sh[tid] += t;
        __syncthreads();
    }
    if (tid < nb) bsum[tid] = sh[tid] - v;        // exclusive
}

__global__ void k_scan3(int* __restrict__ rowptr, const int* __restrict__ bsum,
                        int N, int E) {
    int i = blockIdx.x * blockDim.x + threadIdx.x;
    if (i < N) rowptr[i] += bsum[blockIdx.x * blockDim.x / 256 + (threadIdx.x >= 256)];
    if (i == 0) rowptr[N] = E;
}

__global__ void k_scatter(const int* __restrict__ ei, const int* __restrict__ rowptr,
                          int* __restrict__ fill, int* __restrict__ csr_src, int E) {
    int e = blockIdx.x * blockDim.x + threadIdx.x;
    if (e < E) {
        int d = ei[E + e];
        int slot = rowptr[d] + atomicAdd(&fill[d], 1);
        csr_src[slot] = ei[e];
    }
}

// ============ linear layers (write y = h * dinv) ============

__global__ __launch_bounds__(256) void k_lin1(const float* __restrict__ x,
                                              const float* __restrict__ W1,
                                              const float* __restrict__ dinv,
                                              float* __restrict__ y1, int N) {
    __shared__ float ws[NF * C1];     // 8 KB
    __shared__ float xs[16 * 132];    // padded stride
    int tid = threadIdx.x;
    for (int t = tid; t < NF * C1; t += 256) ws[t] = W1[t];
    int n0 = blockIdx.x * 16;
    for (int t = tid; t < 16 * NF; t += 256) {
        int r = t >> 7, c = t & 127;
        int n = n0 + r;
        xs[r * 132 + c] = (n < N) ? x[(size_t)n * NF + c] : 0.0f;
    }
    __syncthreads();
    int r = tid >> 4, j = tid & 15;   // 16 nodes x 16 outs
    float acc = 0.0f;
#pragma unroll 4
    for (int k = 0; k < NF; ++k) acc += xs[r * 132 + k] * ws[k * C1 + j];
    int n = n0 + r;
    if (n < N) y1[(size_t)n * C1 + j] = acc * dinv[n];
}

__global__ __launch_bounds__(256) void k_lin2(const float* __restrict__ agg1,
                                              const float* __restrict__ b1,
                                              const float* __restrict__ W2,
                                              const float* __restrict__ dinv,
                                              float* __restrict__ y2, int N) {
    __shared__ float ws[C1 * C2];
    __shared__ float hs[8 * C1];
    int tid = threadIdx.x;
    for (int t = tid; t < C1 * C2; t += 256) ws[t] = W2[t];
    int n0 = blockIdx.x * 8;
    if (tid < 8 * C1) {
        int r = tid >> 4, j = tid & 15;
        int n = n0 + r;
        hs[tid] = (n < N) ? fmaxf(agg1[(size_t)n * C1 + j] + b1[j], 0.0f) : 0.0f;
    }
    __syncthreads();
    int r = tid >> 5, i = tid & 31;   // 8 nodes x 32 outs
    float acc = 0.0f;
#pragma unroll
    for (int j = 0; j < C1; ++j) acc += hs[r * C1 + j] * ws[j * C2 + i];
    int n = n0 + r;
    if (n < N) y2[(size_t)n * C2 + i] = acc * dinv[n];
}

// ============ gather aggregation: agg[n] = dinv[n]*(y[n] + sum_{e in row n} y[src]) ============

template <int LOG2C>
__global__ __launch_bounds__(256) void k_gather(const int* __restrict__ rowptr,
                                                const int* __restrict__ csr_src,
                                                const float* __restrict__ dinv,
                                                const float* __restrict__ y,
                                                float* __restrict__ agg, int N) {
    const int C = 1 << LOG2C;
    int tid = threadIdx.x;
    int j = tid & (C - 1);
    int n = blockIdx.x * (256 >> LOG2C) + (tid >> LOG2C);
    if (n >= N) return;
    int k0 = rowptr[n], k1 = rowptr[n + 1];
    float acc0 = y[(size_t)n * C + j];   // self-loop term (already *dinv[n])
    float acc1 = 0.0f;
    int k = k0;
    for (; k + 1 < k1; k += 2) {
        int s0 = csr_src[k], s1 = csr_src[k + 1];
        acc0 += y[(size_t)s0 * C + j];
        acc1 += y[(size_t)s1 * C + j];
    }
    if (k < k1) acc0 += y[(size_t)csr_src[k] * C + j];
    agg[(size_t)n * C + j] = dinv[n] * (acc0 + acc1);
}

// ============ per-graph mean pool (sorted batch) + fused FC ============

__global__ __launch_bounds__(256) void k_pool_fc(const float* __restrict__ agg2,
                                                 const float* __restrict__ b2,
                                                 const int* __restrict__ batch,
                                                 const float* __restrict__ Wfc,
                                                 const float* __restrict__ bfc,
                                                 float* __restrict__ out, int N, int G) {
    int g = blockIdx.x;
    int lo = 0, hi = N;
    while (lo < hi) { int m = (lo + hi) >> 1; if (batch[m] < g) lo = m + 1; else hi = m; }
    int start = lo;
    lo = start; hi = N;
    while (lo < hi) { int m = (lo + hi) >> 1; if (batch[m] < g + 1) lo = m + 1; else hi = m; }
    int end = lo;

    int tid = threadIdx.x;
    int i = tid & 31, r = tid >> 5;
    float bi = b2[i];
    float acc = 0.0f;
    for (int n = start + r; n < end; n += 8)
        acc += fmaxf(agg2[(size_t)n * C2 + i] + bi, 0.0f);

    __shared__ float red[256];
    red[tid] = acc;
    __syncthreads();
    for (int s = 4; s >= 1; s >>= 1) {
        if (r < s) red[tid] += red[tid + s * 32];
        __syncthreads();
    }
    __shared__ float pooled[C2];
    if (tid < C2) {
        float cnt = (float)(end - start);
        pooled[tid] = red[tid] / fmaxf(cnt, 1.0f);
    }
    __syncthreads();
    if (tid < NCLS) {
        float a = bfc[tid];
#pragma unroll
        for (int j = 0; j < C2; ++j) a += pooled[j] * Wfc[j * NCLS + tid];
        out[g * NCLS + tid] = a;
    }
}

extern "C" void kernel_launch(void* const* d_in, const int* in_sizes, int n_in,
                              void* d_out, int out_size, void* d_ws, size_t ws_size,
                              hipStream_t stream) {
    const float* x    = (const float*)d_in[0];
    const int*   ei   = (const int*)d_in[1];
    const int*   batch= (const int*)d_in[2];
    const float* W1   = (const float*)d_in[3];
    const float* b1   = (const float*)d_in[4];
    const float* W2   = (const float*)d_in[5];
    const float* b2   = (const float*)d_in[6];
    const float* Wfc  = (const float*)d_in[7];
    const float* bfc  = (const float*)d_in[8];
    float* out = (float*)d_out;

    const int N = in_sizes[0] / NF;       // 100000
    const int E = in_sizes[1] / 2;        // 3200000
    const int G = out_size / NCLS;        // 256
    const int nb = (N + 255) / 256;       // scan blocks

    // workspace layout (16B-aligned chunks)
    char* p = (char*)d_ws;
    auto alloc = [&](size_t bytes) { char* q = p; p += (bytes + 15) & ~(size_t)15; return q; };
    int*   cnt     = (int*)  alloc((size_t)N * 4);        // histogram, then reused as fill
    float* dinv    = (float*)alloc((size_t)N * 4);
    int*   rowptr  = (int*)  alloc((size_t)(N + 1) * 4);
    int*   bsum    = (int*)  alloc(512 * 4);
    int*   csr_src = (int*)  alloc((size_t)E * 4);
    float* y1      = (float*)alloc((size_t)N * C1 * 4);
    float* agg1    = (float*)alloc((size_t)N * C1 * 4);
    float* y2      = (float*)alloc((size_t)N * C2 * 4);
    float* agg2    = (float*)alloc((size_t)N * C2 * 4);

    const int B = 256;

    // --- CSR build ---
    hipMemsetAsync(cnt, 0, (size_t)N * 4, stream);
    k_hist<<<(E + B - 1) / B, B, 0, stream>>>(ei, cnt, E);
    k_dinv<<<(N + B - 1) / B, B, 0, stream>>>(cnt, dinv, N);
    k_scan1<<<nb, 256, 0, stream>>>(cnt, rowptr, bsum, N);
    k_scan2<<<1, 512, 0, stream>>>(bsum, nb);
    k_scan3<<<nb, 256, 0, stream>>>(rowptr, bsum, N, E);
    hipMemsetAsync(cnt, 0, (size_t)N * 4, stream);        // reuse as fill counters
    k_scatter<<<(E + B - 1) / B, B, 0, stream>>>(ei, rowptr, cnt, csr_src, E);

    // --- layer 1 ---
    k_lin1<<<(N + 15) / 16, B, 0, stream>>>(x, W1, dinv, y1, N);
    k_gather<4><<<(N * C1 + B - 1) / B, B, 0, stream>>>(rowptr, csr_src, dinv, y1, agg1, N);

    // --- layer 2 ---
    k_lin2<<<(N + 7) / 8, B, 0, stream>>>(agg1, b1, W2, dinv, y2, N);
    k_gather<5><<<(N * C2 + B - 1) / B, B, 0, stream>>>(rowptr, csr_src, dinv, y2, agg2, N);

    // --- pool + fc ---
    k_pool_fc<<<G, B, 0, stream>>>(agg2, b2, batch, Wfc, bfc, out, N, G);
}